// Round 7
// baseline (568.375 us; speedup 1.0000x reference)
//
#include <hip/hip_runtime.h>

// B=8, S=2048, F=1024 fp32 in/out.
// out[b,s,:] = diag[b,s] * (value[b,s,:] @ Wv^T)
// diag[b,j] = exp(s_jj - M_j) / sum_i exp(s_ij - M_j),  s_ij = scale * <q_t_i, k_t_j>
// fp16 MFMA 16x16x32, 256x256 tile, BK=64, 8 waves (2Mx4N).
// Pipeline: stage tile t+1 spread through tile t's body; ONE vmcnt(0)+barrier
// gate per K-tile (full drain is required: waves are statically bound to LDS
// halves, so every half is read immediately after the gate -> counted gates
// with a 2-buffer ring are unsound; this is the R5/R6 NaN root cause).

typedef _Float16 f16x8 __attribute__((ext_vector_type(8)));
typedef float    f32x4 __attribute__((ext_vector_type(4)));

#define COLIC 4          // i-chunks for col_stats (8jb x 4ic x 8b = 256 blocks)
#define SCALE 0.03125f   // 1/sqrt(1024)

typedef __attribute__((address_space(1))) const unsigned int g_u32_t;
typedef __attribute__((address_space(3))) unsigned int l_u32_t;

__device__ __forceinline__ void gload16(const _Float16* g, _Float16* l) {
  // async global->LDS, 16 B/lane; LDS dest = wave-uniform base + lane*16 (linear)
  __builtin_amdgcn_global_load_lds((g_u32_t*)g, (l_u32_t*)l, 16, 0, 0);
}

#define VMCNT0() do { asm volatile("s_waitcnt vmcnt(0)" ::: "memory"); \
                      __builtin_amdgcn_sched_barrier(0); } while (0)

// Raw barrier pinned against compiler code motion on BOTH sides.
__device__ __forceinline__ void barx() {
  __builtin_amdgcn_sched_barrier(0);
  __builtin_amdgcn_s_barrier();
  __builtin_amdgcn_sched_barrier(0);
}

// Stage one 128x64 fp16 half-tile (16 KB) into LDS, linear dest, source
// pre-swizzled so LDS[linear] holds logical element at swz(linear),
// swz(a) = a ^ (((a>>7)&7)<<4) on byte offsets (involution, bank-spreading).
__device__ __forceinline__ void stage_half(const _Float16* gbase, _Float16* ldsHalf,
                                           int w, int lane) {
#pragma unroll
  for (int c = 0; c < 2; ++c) {
    const int o = ((w * 2 + c) << 10) + (lane << 4);   // linear byte off 0..16383
    const int row = o >> 7;                            // 0..127
    const int colb = (o & 127) ^ ((row & 7) << 4);     // pre-swizzled source col
    const _Float16* g = gbase + (size_t)row * 1024 + (colb >> 1);
    gload16(g, ldsHalf + ((w * 2 + c) << 9));          // +lane*16B implicit
  }
}

// Batched fp32 -> fp16 conversion: grid.y selects (src,dst) pair.
struct Conv3Args {
  const float* src[3];
  _Float16* dst[3];
};
__global__ __launch_bounds__(256)
void conv3_f32_f16(Conv3Args a, int n8) {
  const float* __restrict__ src = a.src[blockIdx.y];
  _Float16* __restrict__ dst = a.dst[blockIdx.y];
  for (int i = blockIdx.x * 256 + threadIdx.x; i < n8; i += gridDim.x * 256) {
    const float4 x = ((const float4*)src)[2 * i];
    const float4 y = ((const float4*)src)[2 * i + 1];
    f16x8 o;
    o[0] = (_Float16)x.x; o[1] = (_Float16)x.y;
    o[2] = (_Float16)x.z; o[3] = (_Float16)x.w;
    o[4] = (_Float16)y.x; o[5] = (_Float16)y.y;
    o[6] = (_Float16)y.z; o[7] = (_Float16)y.w;
    ((f16x8*)dst)[i] = o;
  }
}

// MODE 0: C16[m][n] = sum_k A[m][k]*Bw[n][k]            (fp16 out)
// MODE 1: C32[m][n] = diag[m] * sum_k A[m][k]*Bw[n][k]  (fp32 out, diag fused)
// MODE 2: col-stats of S = scale * qt @ kt^T : online per-column (m,l) + s_jj
template <int MODE>
__global__ __launch_bounds__(512, 2)
void mfma256(const _Float16* __restrict__ A, const _Float16* __restrict__ Bw,
             _Float16* __restrict__ C16, float* __restrict__ C32,
             float* __restrict__ mpart, float* __restrict__ lpart,
             float* __restrict__ sdiag, int N, int S, int BSz) {
  // [buf][half][128x64 fp16]; halves: 0=A rows0-127, 1=A rows128-255, 2=B0, 3=B1
  __shared__ __align__(16) _Float16 lds[2][4][8192];           // 128 KB
  __shared__ float redM[(MODE == 2) ? 8 : 1][256];             // MODE1: diagS in redM[0]
  __shared__ float redL[(MODE == 2) ? 8 : 1][256];

  const int tid = threadIdx.x;
  const int w = tid >> 6, lane = tid & 63;
  const int wr = w >> 2, wc = w & 3;            // 2M x 4N waves; wave tile 128x64
  const int lr = lane & 15, kq = lane >> 4;

  // Block geometry / operand bases
  int bm = 0, bn = 0, arow0 = 0, brow0 = 0, bb = 0, j0 = 0;
  const _Float16 *Ab, *Bb;
  if (MODE == 2) {
    bb = blockIdx.z;
    j0 = blockIdx.x * 256;
    arow0 = blockIdx.y * (S / COLIC);           // i-chunk start (chunk = 512)
    brow0 = j0;
    Ab = A + (size_t)bb * S * 1024;
    Bb = Bw + (size_t)bb * S * 1024;
  } else {
    bm = blockIdx.x * 256; bn = blockIdx.y * 256;
    arow0 = bm; brow0 = bn;
    Ab = A; Bb = Bw;
  }

  // MODE1: fused combine -> diag for this block's 256 rows (into redM[0]).
  if (MODE == 1) {
    if (tid < 256) {
      const int row = bm + tid;
      float Mx = -3.0e38f;
#pragma unroll
      for (int c = 0; c < COLIC; ++c) Mx = fmaxf(Mx, mpart[(size_t)c * BSz + row]);
      float L = 0.0f;
#pragma unroll
      for (int c = 0; c < COLIC; ++c)
        L += lpart[(size_t)c * BSz + row] * __expf(mpart[(size_t)c * BSz + row] - Mx);
      redM[0][tid] = __expf(sdiag[row] - Mx) / L;
    }
    __syncthreads();
  }

  const int G = (MODE == 2) ? 32 : 16;          // K-tiles (2 i-subtiles for MODE2)

  // stage half-tile ht of K-tile gn into buf[gn&1]
  auto stage_for = [&](int gn, int p) {
    const int ht = (p == 0) ? 0 : (p == 1) ? 2 : (p == 2) ? 3 : 1;
    const int kt = gn & 15;
    const _Float16* gb;
    if (ht < 2) gb = Ab + (size_t)(arow0 + (MODE == 2 ? (gn >> 4) * 256 : 0) + ht * 128) * 1024 + kt * 64;
    else        gb = Bb + (size_t)(brow0 + (ht - 2) * 128) * 1024 + kt * 64;
    stage_half(gb, &lds[gn & 1][ht][0], w, lane);
  };

  // prologue: stage all 4 halves of tile 0
#pragma unroll
  for (int p = 0; p < 4; ++p) stage_for(0, p);

  f32x4 acc[8][4];
  if (MODE != 2) {
#pragma unroll
    for (int mi = 0; mi < 8; ++mi)
#pragma unroll
      for (int ni = 0; ni < 4; ++ni) acc[mi][ni] = (f32x4){0.f, 0.f, 0.f, 0.f};
  }

  float sm[4], sl[4];
  // swizzled col offsets (fp16 elements) for ks=0,1 fragment reads
  const int csw0 = ((kq * 16) ^ ((lr & 7) << 4)) >> 1;
  const int csw1 = ((64 + kq * 16) ^ ((lr & 7) << 4)) >> 1;
  const int browh = (wc & 1) * 64;              // B row base within half

  for (int g = 0; g < G; ++g) {
    const int cur = g & 1;
    if (MODE == 2 && (g & 15) == 0) {
#pragma unroll
      for (int mi = 0; mi < 8; ++mi)
#pragma unroll
        for (int ni = 0; ni < 4; ++ni) acc[mi][ni] = (f32x4){0.f, 0.f, 0.f, 0.f};
      if ((g >> 4) == 0) {
#pragma unroll
        for (int ni = 0; ni < 4; ++ni) { sm[ni] = -3.0e38f; sl[ni] = 0.0f; }
      }
    }
    const _Float16* LA = &lds[cur][wr][0];
    const _Float16* LB = &lds[cur][2 + (wc >> 1)][0];
    f16x8 af[4][2], bf[4][2];

    // ======== single gate per K-tile: full drain + barrier ========
    VMCNT0();
    barx();

    // cluster 1: A rows 0-63 + B rows browh..+31; stage A0(g+1); 16 MFMA
#pragma unroll
    for (int i = 0; i < 4; ++i) {
      af[i][0] = *(const f16x8*)&LA[(i * 16 + lr) * 64 + csw0];
      af[i][1] = *(const f16x8*)&LA[(i * 16 + lr) * 64 + csw1];
    }
#pragma unroll
    for (int n = 0; n < 2; ++n) {
      bf[n][0] = *(const f16x8*)&LB[(browh + n * 16 + lr) * 64 + csw0];
      bf[n][1] = *(const f16x8*)&LB[(browh + n * 16 + lr) * 64 + csw1];
    }
    if (g + 1 < G) stage_for(g + 1, 0);
#pragma unroll
    for (int i = 0; i < 4; ++i)
#pragma unroll
      for (int n = 0; n < 2; ++n) {
        acc[i][n] = __builtin_amdgcn_mfma_f32_16x16x32_f16(af[i][0], bf[n][0], acc[i][n], 0, 0, 0);
        acc[i][n] = __builtin_amdgcn_mfma_f32_16x16x32_f16(af[i][1], bf[n][1], acc[i][n], 0, 0, 0);
      }

    // cluster 2: B rows browh+32..+63; stage B0(g+1); 16 MFMA
#pragma unroll
    for (int n = 2; n < 4; ++n) {
      bf[n][0] = *(const f16x8*)&LB[(browh + n * 16 + lr) * 64 + csw0];
      bf[n][1] = *(const f16x8*)&LB[(browh + n * 16 + lr) * 64 + csw1];
    }
    if (g + 1 < G) stage_for(g + 1, 1);
#pragma unroll
    for (int i = 0; i < 4; ++i)
#pragma unroll
      for (int n = 2; n < 4; ++n) {
        acc[i][n] = __builtin_amdgcn_mfma_f32_16x16x32_f16(af[i][0], bf[n][0], acc[i][n], 0, 0, 0);
        acc[i][n] = __builtin_amdgcn_mfma_f32_16x16x32_f16(af[i][1], bf[n][1], acc[i][n], 0, 0, 0);
      }

    // cluster 3: A rows 64-127; stage B1(g+1); 16 MFMA
#pragma unroll
    for (int i = 0; i < 4; ++i) {
      af[i][0] = *(const f16x8*)&LA[((4 + i) * 16 + lr) * 64 + csw0];
      af[i][1] = *(const f16x8*)&LA[((4 + i) * 16 + lr) * 64 + csw1];
    }
    if (g + 1 < G) stage_for(g + 1, 2);
#pragma unroll
    for (int i = 0; i < 4; ++i)
#pragma unroll
      for (int n = 0; n < 2; ++n) {
        acc[4 + i][n] = __builtin_amdgcn_mfma_f32_16x16x32_f16(af[i][0], bf[n][0], acc[4 + i][n], 0, 0, 0);
        acc[4 + i][n] = __builtin_amdgcn_mfma_f32_16x16x32_f16(af[i][1], bf[n][1], acc[4 + i][n], 0, 0, 0);
      }

    // cluster 4: stage A1(g+1); 16 MFMA
    if (g + 1 < G) stage_for(g + 1, 3);
#pragma unroll
    for (int i = 0; i < 4; ++i)
#pragma unroll
      for (int n = 2; n < 4; ++n) {
        acc[4 + i][n] = __builtin_amdgcn_mfma_f32_16x16x32_f16(af[i][0], bf[n][0], acc[4 + i][n], 0, 0, 0);
        acc[4 + i][n] = __builtin_amdgcn_mfma_f32_16x16x32_f16(af[i][1], bf[n][1], acc[4 + i][n], 0, 0, 0);
      }

    // MODE2: end of i-subtile -> diag capture + online (m,l) update (reg-only)
    if (MODE == 2 && (g & 15) == 15) {
      const int i0 = arow0 + (g >> 4) * 256;
      if (i0 == j0 && wr == (wc >> 1) && kq == (lr >> 2)) {
#pragma unroll
        for (int ni = 0; ni < 4; ++ni) {
          const int mi = (wc & 1) * 4 + ni;
          sdiag[(size_t)bb * S + j0 + wc * 64 + ni * 16 + lr] = acc[mi][ni][lr & 3] * SCALE;
        }
      }
#pragma unroll
      for (int ni = 0; ni < 4; ++ni) {
        float tm = -3.0e38f;
#pragma unroll
        for (int mi = 0; mi < 8; ++mi)
#pragma unroll
          for (int jj = 0; jj < 4; ++jj) tm = fmaxf(tm, acc[mi][ni][jj]);
        tm *= SCALE;
        const float mn = fmaxf(sm[ni], tm);
        float add = 0.0f;
#pragma unroll
        for (int mi = 0; mi < 8; ++mi)
#pragma unroll
          for (int jj = 0; jj < 4; ++jj) add += __expf(acc[mi][ni][jj] * SCALE - mn);
        sl[ni] = sl[ni] * __expf(sm[ni] - mn) + add;
        sm[ni] = mn;
      }
    }
  }

  // ---------------- epilogues ----------------
  if (MODE == 2) {
    __syncthreads();
    const int p8 = wr * 4 + kq;
#pragma unroll
    for (int ni = 0; ni < 4; ++ni) {
      const int col = wc * 64 + ni * 16 + lr;
      redM[p8][col] = sm[ni];
      redL[p8][col] = sl[ni];
    }
    __syncthreads();
    if (tid < 256) {
      float M = -3.0e38f;
#pragma unroll
      for (int q = 0; q < 8; ++q) M = fmaxf(M, redM[q][tid]);
      float L = 0.0f;
#pragma unroll
      for (int q = 0; q < 8; ++q) L += redL[q][tid] * __expf(redM[q][tid] - M);
      const size_t idx = ((size_t)blockIdx.y * gridDim.z + bb) * S + j0 + tid;
      mpart[idx] = M;
      lpart[idx] = L;
    }
  } else {
#pragma unroll
    for (int mi = 0; mi < 8; ++mi) {
#pragma unroll
      for (int jj = 0; jj < 4; ++jj) {
        const int rloc = wr * 128 + mi * 16 + kq * 4 + jj;
        const int row = bm + rloc;
        float s = 1.0f;
        if (MODE == 1) s = redM[0][rloc];
#pragma unroll
        for (int ni = 0; ni < 4; ++ni) {
          const int col = bn + wc * 64 + ni * 16 + lr;
          if (MODE == 0) C16[(size_t)row * N + col] = (_Float16)acc[mi][ni][jj];
          else           C32[(size_t)row * N + col] = acc[mi][ni][jj] * s;
        }
      }
    }
  }
}

extern "C" void kernel_launch(void* const* d_in, const int* in_sizes, int n_in,
                              void* d_out, int out_size, void* d_ws, size_t ws_size,
                              hipStream_t stream) {
  const float* query = (const float*)d_in[0];
  const float* key   = (const float*)d_in[1];
  const float* value = (const float*)d_in[2];
  const float* Wq    = (const float*)d_in[3];
  const float* Wk    = (const float*)d_in[4];
  const float* Wv    = (const float*)d_in[5];

  const int F = 1024;
  const int BS = in_sizes[0] / F;   // 16384
  const int B = 8;
  const int S = BS / B;             // 2048

  // ws: q16,k16,v16 [BS*F] wq16,wk16,wv16 [F*F] mpart,lpart [COLIC*BS] sdiag [BS]
  _Float16* q16  = (_Float16*)d_ws;
  _Float16* k16  = q16 + (size_t)BS * F;
  _Float16* v16  = k16 + (size_t)BS * F;
  _Float16* wq16 = v16 + (size_t)BS * F;
  _Float16* wk16 = wq16 + (size_t)F * F;
  _Float16* wv16 = wk16 + (size_t)F * F;
  float* mpart = (float*)(wv16 + (size_t)F * F);
  float* lpart = mpart + (size_t)COLIC * BS;
  float* sdiag = lpart + (size_t)COLIC * BS;

  // qt16/kt16 parked in d_out (exactly BS*F*4 bytes); dead before final GEMM writes it.
  _Float16* qt16 = (_Float16*)d_out;
  _Float16* kt16 = qt16 + (size_t)BS * F;

  const int n8x = BS * F / 8, n8w = F * F / 8;

  Conv3Args ax; ax.src[0] = query; ax.src[1] = key; ax.src[2] = value;
  ax.dst[0] = q16; ax.dst[1] = k16; ax.dst[2] = v16;
  conv3_f32_f16<<<dim3(2048, 3), dim3(256), 0, stream>>>(ax, n8x);

  Conv3Args aw; aw.src[0] = Wq; aw.src[1] = Wk; aw.src[2] = Wv;
  aw.dst[0] = wq16; aw.dst[1] = wk16; aw.dst[2] = wv16;
  conv3_f32_f16<<<dim3(512, 3), dim3(256), 0, stream>>>(aw, n8w);

  const dim3 ggrid(BS / 256, F / 256);  // 64 x 4 = 256 blocks
  mfma256<0><<<ggrid, dim3(512), 0, stream>>>(q16, wq16, qt16, nullptr,
                                              nullptr, nullptr, nullptr, F, S, BS);
  mfma256<0><<<ggrid, dim3(512), 0, stream>>>(k16, wk16, kt16, nullptr,
                                              nullptr, nullptr, nullptr, F, S, BS);

  const dim3 sgrid(S / 256, COLIC, B);  // 8 x 4 x 8 = 256 blocks
  mfma256<2><<<sgrid, dim3(512), 0, stream>>>(qt16, kt16, nullptr, nullptr,
                                              mpart, lpart, sdiag, F, S, BS);

  mfma256<1><<<ggrid, dim3(512), 0, stream>>>(v16, wv16, nullptr, (float*)d_out,
                                              mpart, lpart, sdiag, F, S, BS);
}

// Round 8
// 376.476 us; speedup vs baseline: 1.5097x; 1.5097x over previous
//
#include <hip/hip_runtime.h>

// B=8, S=2048, F=1024 fp32 in/out.
// out[b,s,:] = diag[b,s] * (value[b,s,:] @ Wv^T)
// diag[b,j] = exp(s_jj - M_j) / sum_i exp(s_ij - M_j),  s_ij = scale * <q_t_i, k_t_j>
// All dense stages in fp16 MFMA (16x16x32, fp32 accum), m97-style 128x128 tiles.
// col_stats uses T3-minimum 2-phase: double-buffered LDS, stage(t+1) issued at
// top of iter t, ONE __syncthreads per K-step (implicit vmcnt0 drain = the gate).

typedef _Float16 f16x8 __attribute__((ext_vector_type(8)));
typedef float    f32x4 __attribute__((ext_vector_type(4)));

#define COLIC 8          // i-chunks for col_stats grid (1024 blocks)
#define SCALE 0.03125f   // 1/sqrt(1024), exact power of two

typedef __attribute__((address_space(1))) const unsigned int g_u32_t;
typedef __attribute__((address_space(3))) unsigned int l_u32_t;

__device__ __forceinline__ void gload16(const _Float16* g, _Float16* l) {
  // async global->LDS, 16 B per lane; LDS dest = wave-uniform base + lane*16
  __builtin_amdgcn_global_load_lds((g_u32_t*)g, (l_u32_t*)l, 16, 0, 0);
}

// Stage a 128x32 fp16 tile (global rows stride ldk) into LDS row-major [128][32].
__device__ __forceinline__ void stage_tile(const _Float16* gbase, int ldk,
                                           _Float16* lds, int w, int lane) {
#pragma unroll
  for (int c = 0; c < 2; ++c) {
    const int blk = c * 4 + w;                  // 0..7, wave-uniform
    const int r = (blk << 4) + (lane >> 2);     // row 0..127
    const _Float16* g = gbase + (size_t)r * ldk + ((lane & 3) << 3);
    gload16(g, lds + blk * 512);                // 512 fp16 = 1024 B per wave-call
  }
}

// Batched fp32 -> fp16 conversion: grid.y selects (src,dst) pair.
struct Conv3Args {
  const float* src[3];
  _Float16* dst[3];
};
__global__ __launch_bounds__(256)
void conv3_f32_f16(Conv3Args a, int n8) {
  const float* __restrict__ src = a.src[blockIdx.y];
  _Float16* __restrict__ dst = a.dst[blockIdx.y];
  for (int i = blockIdx.x * 256 + threadIdx.x; i < n8; i += gridDim.x * 256) {
    const float4 x = ((const float4*)src)[2 * i];
    const float4 y = ((const float4*)src)[2 * i + 1];
    f16x8 o;
    o[0] = (_Float16)x.x; o[1] = (_Float16)x.y;
    o[2] = (_Float16)x.z; o[3] = (_Float16)x.w;
    o[4] = (_Float16)y.x; o[5] = (_Float16)y.y;
    o[6] = (_Float16)y.z; o[7] = (_Float16)y.w;
    ((f16x8*)dst)[i] = o;
  }
}

// C[m][n] = sum_k A[m][k] * B[n][k];  A: MxK, B: NxK, both fp16 row-major.
// F16OUT=1: write fp16 C16.
// F16OUT=0: write fp32 C32 scaled by diag[m], diag computed inline from
//           (mpart, lpart, sdiag) in the prologue (fused combine).
// (R4-identical; known 897 TF; m99/m100: dbuf is null on this structure.)
template <int F16OUT>
__global__ __launch_bounds__(256)
void gemm_mfma(const _Float16* __restrict__ A, const _Float16* __restrict__ B,
               _Float16* __restrict__ C16, float* __restrict__ C32,
               const float* __restrict__ mpart, const float* __restrict__ lpart,
               const float* __restrict__ sdiag, int BSz,
               int M, int N, int Kd) {
  __shared__ __align__(16) _Float16 As[128 * 32];
  __shared__ __align__(16) _Float16 Bs[128 * 32];
  __shared__ float diagS[128];
  const int tid = threadIdx.x;
  const int w = tid >> 6, lane = tid & 63;
  const int wr = w >> 1, wc = w & 1;          // 2x2 waves over 128x128
  const int lr = lane & 15, kq = lane >> 4;
  const int bm = blockIdx.x * 128, bn = blockIdx.y * 128;

  if (!F16OUT && tid < 128) {
    const int row = bm + tid;
    float Mx = -3.0e38f;
#pragma unroll
    for (int c = 0; c < COLIC; ++c) Mx = fmaxf(Mx, mpart[(size_t)c * BSz + row]);
    float L = 0.0f;
#pragma unroll
    for (int c = 0; c < COLIC; ++c)
      L += lpart[(size_t)c * BSz + row] * __expf(mpart[(size_t)c * BSz + row] - Mx);
    diagS[tid] = __expf(sdiag[row] - Mx) / L;
  }

  f32x4 acc[4][4] = {};
  for (int k0 = 0; k0 < Kd; k0 += 32) {
    stage_tile(A + (size_t)bm * Kd + k0, Kd, As, w, lane);
    stage_tile(B + (size_t)bn * Kd + k0, Kd, Bs, w, lane);
    __syncthreads();
    f16x8 af[4], bf[4];
#pragma unroll
    for (int mi = 0; mi < 4; ++mi)
      af[mi] = *(const f16x8*)&As[(wr * 64 + mi * 16 + lr) * 32 + kq * 8];
#pragma unroll
    for (int ni = 0; ni < 4; ++ni)
      bf[ni] = *(const f16x8*)&Bs[(wc * 64 + ni * 16 + lr) * 32 + kq * 8];
#pragma unroll
    for (int mi = 0; mi < 4; ++mi)
#pragma unroll
      for (int ni = 0; ni < 4; ++ni)
        acc[mi][ni] = __builtin_amdgcn_mfma_f32_16x16x32_f16(af[mi], bf[ni], acc[mi][ni], 0, 0, 0);
    __syncthreads();  // also keeps diagS visible for epilogue
  }
  // C/D layout: col = lane&15, row = (lane>>4)*4 + reg  [m89-verified]
#pragma unroll
  for (int mi = 0; mi < 4; ++mi) {
#pragma unroll
    for (int j = 0; j < 4; ++j) {
      const int rloc = wr * 64 + mi * 16 + kq * 4 + j;
      const int row = bm + rloc;
      float s = 1.0f;
      if (!F16OUT) s = diagS[rloc];
#pragma unroll
      for (int ni = 0; ni < 4; ++ni) {
        const int col = bn + wc * 64 + ni * 16 + lr;
        if (F16OUT) C16[(size_t)row * N + col] = (_Float16)acc[mi][ni][j];
        else        C32[(size_t)row * N + col] = acc[mi][ni][j] * s;
      }
    }
  }
}

// Per (b, j-tile 128, i-chunk): S-tile = Qt * Kt^T via MFMA (never materialized),
// online per-column (max, sumexp) over i, diagonal score capture.
// 2-phase pipeline: stage(t+1) at top of iter t, compute buf[t], one barrier.
// Race-free by __syncthreads semantics: buf[t+1 & 1] was last read in iter t-1,
// whose reads retired at the t-1-closing barrier every wave passed before
// issuing this stage.
__global__ __launch_bounds__(256)
void col_stats_mfma(const _Float16* __restrict__ qt, const _Float16* __restrict__ kt,
                    float* __restrict__ mpart, float* __restrict__ lpart,
                    float* __restrict__ sdiag, int S, int Fd, int chunk) {
  __shared__ __align__(16) _Float16 Qs[2][128 * 32];
  __shared__ __align__(16) _Float16 Ks[2][128 * 32];
  __shared__ float redM[8][128];
  __shared__ float redL[8][128];
  const int b = blockIdx.z, jb = blockIdx.x, ic = blockIdx.y;
  const int j0 = jb * 128;
  const _Float16* Q = qt + (size_t)b * S * Fd;
  const _Float16* K = kt + (size_t)b * S * Fd;
  const int tid = threadIdx.x;
  const int w = tid >> 6, lane = tid & 63;
  const int wr = w >> 1, wc = w & 1;
  const int lr = lane & 15, kq = lane >> 4;

  float m[4], l[4];
#pragma unroll
  for (int ni = 0; ni < 4; ++ni) { m[ni] = -3.0e38f; l[ni] = 0.0f; }

  const int nit = chunk >> 7;        // i-tiles per block (chunk=256 -> 2)
  const int G = nit << 5;            // K-steps total (Fd==1024 -> 32 per i-tile)

  // prologue: stage step 0
  stage_tile(Q + (size_t)(ic * chunk) * Fd, Fd, Qs[0], w, lane);
  stage_tile(K + (size_t)j0 * Fd, Fd, Ks[0], w, lane);
  __syncthreads();

  int cur = 0;
  f32x4 acc[4][4];
  for (int gg = 0; gg < G; ++gg) {
    if ((gg & 31) == 0) {            // new i-tile: reset accumulator (F==1024)
#pragma unroll
      for (int mi = 0; mi < 4; ++mi)
#pragma unroll
        for (int ni = 0; ni < 4; ++ni) acc[mi][ni] = (f32x4){0.f, 0.f, 0.f, 0.f};
    }
    // issue next step's stage FIRST (latency hides under this step's compute)
    if (gg + 1 < G) {
      const int it1 = (gg + 1) >> 5;
      const int kk1 = ((gg + 1) & 31) << 5;
      stage_tile(Q + (size_t)(ic * chunk + it1 * 128) * Fd + kk1, Fd, Qs[cur ^ 1], w, lane);
      stage_tile(K + (size_t)j0 * Fd + kk1, Fd, Ks[cur ^ 1], w, lane);
    }
    // compute from buf[cur]
    f16x8 af[4], bf[4];
#pragma unroll
    for (int mi = 0; mi < 4; ++mi)
      af[mi] = *(const f16x8*)&Qs[cur][(wr * 64 + mi * 16 + lr) * 32 + kq * 8];
#pragma unroll
    for (int ni = 0; ni < 4; ++ni)
      bf[ni] = *(const f16x8*)&Ks[cur][(wc * 64 + ni * 16 + lr) * 32 + kq * 8];
#pragma unroll
    for (int mi = 0; mi < 4; ++mi)
#pragma unroll
      for (int ni = 0; ni < 4; ++ni)
        acc[mi][ni] = __builtin_amdgcn_mfma_f32_16x16x32_f16(af[mi], bf[ni], acc[mi][ni], 0, 0, 0);

    // end of i-tile: diag capture + online (m,l) update (register-only; also
    // gives the in-flight stage extra time before the barrier drain)
    if ((gg & 31) == 31) {
      const int i0 = ic * chunk + (gg >> 5) * 128;
      if (i0 == j0 && wr == wc && (lr >> 2) == kq) {
        const int j = lr & 3;
#pragma unroll
        for (int jj = 0; jj < 4; ++jj)
          sdiag[(size_t)b * S + j0 + wc * 64 + jj * 16 + lr] = acc[jj][jj][j] * SCALE;
      }
#pragma unroll
      for (int ni = 0; ni < 4; ++ni) {
        float tm = -3.0e38f;
#pragma unroll
        for (int mi = 0; mi < 4; ++mi)
#pragma unroll
          for (int jj = 0; jj < 4; ++jj) tm = fmaxf(tm, acc[mi][ni][jj]);
        tm *= SCALE;  // scale>0: max commutes with scaling
        const float mn = fmaxf(m[ni], tm);
        float add = 0.0f;
#pragma unroll
        for (int mi = 0; mi < 4; ++mi)
#pragma unroll
          for (int jj = 0; jj < 4; ++jj) add += __expf(acc[mi][ni][jj] * SCALE - mn);
        l[ni] = l[ni] * __expf(m[ni] - mn) + add;
        m[ni] = mn;
      }
    }
    __syncthreads();                 // drains stage(gg+1), retires cur reads
    cur ^= 1;
  }

  // Cross-lane reduce: 8 partials per column (wr x kq), via LDS.
  const int p = wr * 4 + kq;
#pragma unroll
  for (int ni = 0; ni < 4; ++ni) {
    const int col = wc * 64 + ni * 16 + lr;
    redM[p][col] = m[ni];
    redL[p][col] = l[ni];
  }
  __syncthreads();
  if (tid < 128) {
    float M = -3.0e38f;
#pragma unroll
    for (int q = 0; q < 8; ++q) M = fmaxf(M, redM[q][tid]);
    float L = 0.0f;
#pragma unroll
    for (int q = 0; q < 8; ++q) L += redL[q][tid] * __expf(redM[q][tid] - M);
    const size_t idx = ((size_t)ic * gridDim.z + b) * S + j0 + tid;
    mpart[idx] = M;
    lpart[idx] = L;
  }
}

extern "C" void kernel_launch(void* const* d_in, const int* in_sizes, int n_in,
                              void* d_out, int out_size, void* d_ws, size_t ws_size,
                              hipStream_t stream) {
  const float* query = (const float*)d_in[0];
  const float* key   = (const float*)d_in[1];
  const float* value = (const float*)d_in[2];
  const float* Wq    = (const float*)d_in[3];
  const float* Wk    = (const float*)d_in[4];
  const float* Wv    = (const float*)d_in[5];

  const int F = 1024;
  const int BS = in_sizes[0] / F;   // 16384
  const int B = 8;
  const int S = BS / B;             // 2048

  // ws: q16,k16,v16 [BS*F each] wq16,wk16,wv16 [F*F each]
  //     mpart,lpart [COLIC*BS] sdiag [BS]   ~108 MB total
  _Float16* q16  = (_Float16*)d_ws;
  _Float16* k16  = q16 + (size_t)BS * F;
  _Float16* v16  = k16 + (size_t)BS * F;
  _Float16* wq16 = v16 + (size_t)BS * F;
  _Float16* wk16 = wq16 + (size_t)F * F;
  _Float16* wv16 = wk16 + (size_t)F * F;
  float* mpart = (float*)(wv16 + (size_t)F * F);
  float* lpart = mpart + (size_t)COLIC * BS;
  float* sdiag = lpart + (size_t)COLIC * BS;

  // qt16/kt16 parked in d_out (exactly BS*F*4 bytes); dead before final GEMM writes it.
  _Float16* qt16 = (_Float16*)d_out;
  _Float16* kt16 = qt16 + (size_t)BS * F;

  const dim3 blk(256);
  const int n8x = BS * F / 8, n8w = F * F / 8;

  Conv3Args ax; ax.src[0] = query; ax.src[1] = key; ax.src[2] = value;
  ax.dst[0] = q16; ax.dst[1] = k16; ax.dst[2] = v16;
  conv3_f32_f16<<<dim3(2048, 3), blk, 0, stream>>>(ax, n8x);

  Conv3Args aw; aw.src[0] = Wq; aw.src[1] = Wk; aw.src[2] = Wv;
  aw.dst[0] = wq16; aw.dst[1] = wk16; aw.dst[2] = wv16;
  conv3_f32_f16<<<dim3(512, 3), blk, 0, stream>>>(aw, n8w);

  const dim3 ggrid(BS / 128, F / 128);  // 128 x 8 = 1024 blocks
  gemm_mfma<1><<<ggrid, blk, 0, stream>>>(q16, wq16, qt16, (float*)nullptr,
                                          (const float*)nullptr, (const float*)nullptr,
                                          (const float*)nullptr, BS, BS, F, F);
  gemm_mfma<1><<<ggrid, blk, 0, stream>>>(k16, wk16, kt16, (float*)nullptr,
                                          (const float*)nullptr, (const float*)nullptr,
                                          (const float*)nullptr, BS, BS, F, F);

  const dim3 sgrid(S / 128, COLIC, B);  // 16 x 8 x 8 = 1024 blocks
  col_stats_mfma<<<sgrid, blk, 0, stream>>>(qt16, kt16, mpart, lpart, sdiag,
                                            S, F, S / COLIC);

  gemm_mfma<0><<<ggrid, blk, 0, stream>>>(v16, wv16, (_Float16*)nullptr, (float*)d_out,
                                          mpart, lpart, sdiag, BS, BS, F, F);
}

// Round 9
// 307.964 us; speedup vs baseline: 1.8456x; 1.2225x over previous
//
#include <hip/hip_runtime.h>

// B=8, S=2048, F=1024 fp32 in/out.
// out[b,s,:] = diag[b,s] * (value[b,s,:] @ Wv^T)
// diag[b,j] = exp(s_jj - M_j) / sum_i exp(s_ij - M_j),  s_ij = scale * <q_t_i, k_t_j>
// fp16 MFMA 16x16x32, m97-style 128x128 tiles.
// - GEMMs read fp32 A directly (reg-staged convert + early-issued loads, T14);
//   B operand = pre-converted fp16 weights via global_load_lds.
// - col_stats: BK=64, single-buffered, both-sides XOR-swizzled LDS (rule #21).

typedef _Float16 f16x8 __attribute__((ext_vector_type(8)));
typedef float    f32x4 __attribute__((ext_vector_type(4)));

#define COLIC 8          // i-chunks for col_stats grid (16 x 8 x 8 = 1024 blocks)
#define SCALE 0.03125f   // 1/sqrt(1024), exact power of two

typedef __attribute__((address_space(1))) const unsigned int g_u32_t;
typedef __attribute__((address_space(3))) unsigned int l_u32_t;

__device__ __forceinline__ void gload16(const _Float16* g, _Float16* l) {
  // async global->LDS, 16 B per lane; LDS dest = wave-uniform base + lane*16
  __builtin_amdgcn_global_load_lds((g_u32_t*)g, (l_u32_t*)l, 16, 0, 0);
}

// Stage a 128x32 fp16 tile (rows stride ldk) into LDS row-major [128][32]. (R4)
__device__ __forceinline__ void stage_tile(const _Float16* gbase, int ldk,
                                           _Float16* lds, int w, int lane) {
#pragma unroll
  for (int c = 0; c < 2; ++c) {
    const int blk = c * 4 + w;                  // 0..7, wave-uniform
    const int r = (blk << 4) + (lane >> 2);     // row 0..127
    const _Float16* g = gbase + (size_t)r * ldk + ((lane & 3) << 3);
    gload16(g, lds + blk * 512);                // 1 KB per wave-call
  }
}

// Stage a 128x64 fp16 tile into LDS [128][64] with pre-swizzled SOURCE:
// LDS linear byte o holds logical col (o&127) ^ ((row&7)<<4)  (involution).
__device__ __forceinline__ void stage_tile64(const _Float16* gbase, int ldk,
                                             _Float16* lds, int w, int lane) {
#pragma unroll
  for (int c = 0; c < 4; ++c) {
    const int blk = c * 4 + w;                  // 0..15, wave-uniform
    const int o = (blk << 10) + (lane << 4);    // linear byte offset 0..16383
    const int row = o >> 7;                     // 0..127 (row = 128 B)
    const int colb = (o & 127) ^ ((row & 7) << 4);
    gload16(gbase + (size_t)row * ldk + (colb >> 1), lds + (blk << 9));
  }
}

// Batched fp32 -> fp16 conversion (weights only now): grid.y selects pair.
struct Conv3Args {
  const float* src[3];
  _Float16* dst[3];
};
__global__ __launch_bounds__(256)
void conv3_f32_f16(Conv3Args a, int n8) {
  const float* __restrict__ src = a.src[blockIdx.y];
  _Float16* __restrict__ dst = a.dst[blockIdx.y];
  for (int i = blockIdx.x * 256 + threadIdx.x; i < n8; i += gridDim.x * 256) {
    const float4 x = ((const float4*)src)[2 * i];
    const float4 y = ((const float4*)src)[2 * i + 1];
    f16x8 o;
    o[0] = (_Float16)x.x; o[1] = (_Float16)x.y;
    o[2] = (_Float16)x.z; o[3] = (_Float16)x.w;
    o[4] = (_Float16)y.x; o[5] = (_Float16)y.y;
    o[6] = (_Float16)y.z; o[7] = (_Float16)y.w;
    ((f16x8*)dst)[i] = o;
  }
}

// C[m][n] = sum_k A[m][k] * B[n][k];  A: MxK fp32 (converted in-kernel), B: NxK fp16.
// F16OUT=1: write fp16 C16.  F16OUT=0: fp32 C32 scaled by fused-combine diag[m].
template <int F16OUT>
__global__ __launch_bounds__(256)
void gemm_mfma(const float* __restrict__ Af, const _Float16* __restrict__ Bh,
               _Float16* __restrict__ C16, float* __restrict__ C32,
               const float* __restrict__ mpart, const float* __restrict__ lpart,
               const float* __restrict__ sdiag, int BSz,
               int M, int N, int Kd) {
  __shared__ __align__(16) _Float16 As[128 * 32];
  __shared__ __align__(16) _Float16 Bs[128 * 32];
  __shared__ float diagS[128];
  const int tid = threadIdx.x;
  const int w = tid >> 6, lane = tid & 63;
  const int wr = w >> 1, wc = w & 1;          // 2x2 waves over 128x128
  const int lr = lane & 15, kq = lane >> 4;
  const int bm = blockIdx.x * 128, bn = blockIdx.y * 128;

  if (!F16OUT && tid < 128) {
    const int row = bm + tid;
    float Mx = -3.0e38f;
#pragma unroll
    for (int c = 0; c < COLIC; ++c) Mx = fmaxf(Mx, mpart[(size_t)c * BSz + row]);
    float L = 0.0f;
#pragma unroll
    for (int c = 0; c < COLIC; ++c)
      L += lpart[(size_t)c * BSz + row] * __expf(mpart[(size_t)c * BSz + row] - Mx);
    diagS[tid] = __expf(sdiag[row] - Mx) / L;
  }

  // A reg-stage geometry: blk = c*4+w covers rows blk*16..+15, lane>>2 row within,
  // (lane&3)*8 fp32 cols; ds_write_b128 to As[blk*512 + lane*8] == As[row*32+col].
  const int ar = lane >> 2;
  const int ac = (lane & 3) << 3;
  float4 pa[2][2];
  // prologue: issue A loads for k0=0
#pragma unroll
  for (int c = 0; c < 2; ++c) {
    const int row = bm + (c * 4 + w) * 16 + ar;
    const float4* p = (const float4*)(Af + (size_t)row * Kd + ac);
    pa[c][0] = p[0]; pa[c][1] = p[1];
  }

  f32x4 acc[4][4] = {};
  for (int k0 = 0; k0 < Kd; k0 += 32) {
    // convert + LDS-write current A half-tiles
#pragma unroll
    for (int c = 0; c < 2; ++c) {
      const int blk = c * 4 + w;
      f16x8 v;
      v[0] = (_Float16)pa[c][0].x; v[1] = (_Float16)pa[c][0].y;
      v[2] = (_Float16)pa[c][0].z; v[3] = (_Float16)pa[c][0].w;
      v[4] = (_Float16)pa[c][1].x; v[5] = (_Float16)pa[c][1].y;
      v[6] = (_Float16)pa[c][1].z; v[7] = (_Float16)pa[c][1].w;
      *(f16x8*)&As[blk * 512 + lane * 8] = v;
    }
    // B via async global->LDS
    stage_tile(Bh + (size_t)bn * Kd + k0, Kd, Bs, w, lane);
    // issue next A loads early (latency hides under compute; regs live across)
    const int kn = (k0 + 32 < Kd) ? k0 + 32 : 0;
#pragma unroll
    for (int c = 0; c < 2; ++c) {
      const int row = bm + (c * 4 + w) * 16 + ar;
      const float4* p = (const float4*)(Af + (size_t)row * Kd + kn + ac);
      pa[c][0] = p[0]; pa[c][1] = p[1];
    }
    __syncthreads();   // drains ds_write (lgkm) + gload_lds (vm)
    f16x8 af[4], bf[4];
#pragma unroll
    for (int mi = 0; mi < 4; ++mi)
      af[mi] = *(const f16x8*)&As[(wr * 64 + mi * 16 + lr) * 32 + kq * 8];
#pragma unroll
    for (int ni = 0; ni < 4; ++ni)
      bf[ni] = *(const f16x8*)&Bs[(wc * 64 + ni * 16 + lr) * 32 + kq * 8];
#pragma unroll
    for (int mi = 0; mi < 4; ++mi)
#pragma unroll
      for (int ni = 0; ni < 4; ++ni)
        acc[mi][ni] = __builtin_amdgcn_mfma_f32_16x16x32_f16(af[mi], bf[ni], acc[mi][ni], 0, 0, 0);
    __syncthreads();
  }
  // C/D layout: col = lane&15, row = (lane>>4)*4 + reg  [m89-verified]
#pragma unroll
  for (int mi = 0; mi < 4; ++mi) {
#pragma unroll
    for (int j = 0; j < 4; ++j) {
      const int rloc = wr * 64 + mi * 16 + kq * 4 + j;
      const int row = bm + rloc;
      float s = 1.0f;
      if (!F16OUT) s = diagS[rloc];
#pragma unroll
      for (int ni = 0; ni < 4; ++ni) {
        const int col = bn + wc * 64 + ni * 16 + lr;
        if (F16OUT) C16[(size_t)row * N + col] = (_Float16)acc[mi][ni][j];
        else        C32[(size_t)row * N + col] = acc[mi][ni][j] * s;
      }
    }
  }
}

// Per (b, j-tile 128, i-chunk): S-tile = Qt * Kt^T via MFMA (never materialized),
// online per-column (max, sumexp) over i, diag capture. BK=64, single-buffered,
// XOR-swizzled LDS (write: pre-swizzled source; read: same XOR).
__global__ __launch_bounds__(256)
void col_stats_mfma(const _Float16* __restrict__ qt, const _Float16* __restrict__ kt,
                    float* __restrict__ mpart, float* __restrict__ lpart,
                    float* __restrict__ sdiag, int S, int Fd, int chunk) {
  __shared__ __align__(16) _Float16 Qs[128 * 64];   // 16 KB, rows = 128 B
  __shared__ __align__(16) _Float16 Ks[128 * 64];
  __shared__ float redM[8][128];
  __shared__ float redL[8][128];
  const int b = blockIdx.z, jb = blockIdx.x, ic = blockIdx.y;
  const int j0 = jb * 128;
  const _Float16* Q = qt + (size_t)b * S * Fd;
  const _Float16* K = kt + (size_t)b * S * Fd;
  const int tid = threadIdx.x;
  const int w = tid >> 6, lane = tid & 63;
  const int wr = w >> 1, wc = w & 1;
  const int lr = lane & 15, kq = lane >> 4;
  const int swz = (lr & 7) << 4;               // read-side XOR (rows == lr mod 8)

  float m[4], l[4];
#pragma unroll
  for (int ni = 0; ni < 4; ++ni) { m[ni] = -3.0e38f; l[ni] = 0.0f; }

  for (int it = 0; it < chunk >> 7; ++it) {
    const int i0 = ic * chunk + (it << 7);
    f32x4 acc[4][4] = {};
    for (int k0 = 0; k0 < Fd; k0 += 64) {
      stage_tile64(Q + (size_t)i0 * Fd + k0, Fd, Qs, w, lane);
      stage_tile64(K + (size_t)j0 * Fd + k0, Fd, Ks, w, lane);
      __syncthreads();
      f16x8 af[4][2], bf[4][2];
#pragma unroll
      for (int mi = 0; mi < 4; ++mi) {
        const int ro = (wr * 64 + mi * 16 + lr) << 7;   // row byte base
        af[mi][0] = *(const f16x8*)&Qs[(ro + ((kq * 16) ^ swz)) >> 1];
        af[mi][1] = *(const f16x8*)&Qs[(ro + ((64 + kq * 16) ^ swz)) >> 1];
      }
#pragma unroll
      for (int ni = 0; ni < 4; ++ni) {
        const int ro = (wc * 64 + ni * 16 + lr) << 7;
        bf[ni][0] = *(const f16x8*)&Ks[(ro + ((kq * 16) ^ swz)) >> 1];
        bf[ni][1] = *(const f16x8*)&Ks[(ro + ((64 + kq * 16) ^ swz)) >> 1];
      }
#pragma unroll
      for (int ks = 0; ks < 2; ++ks)
#pragma unroll
        for (int mi = 0; mi < 4; ++mi)
#pragma unroll
          for (int ni = 0; ni < 4; ++ni)
            acc[mi][ni] = __builtin_amdgcn_mfma_f32_16x16x32_f16(af[mi][ks], bf[ni][ks], acc[mi][ni], 0, 0, 0);
      __syncthreads();
    }
    // Diagonal capture (i-tile == j-tile, diagonal micro-fragments).
    if (i0 == j0 && wr == wc && (lr >> 2) == kq) {
      const int j = lr & 3;
#pragma unroll
      for (int jj = 0; jj < 4; ++jj)
        sdiag[(size_t)b * S + j0 + wc * 64 + jj * 16 + lr] = acc[jj][jj][j] * SCALE;
    }
    // Online (m,l) update: per lane, 4 columns (ni), 16 i-values each.
#pragma unroll
    for (int ni = 0; ni < 4; ++ni) {
      float tm = -3.0e38f;
#pragma unroll
      for (int mi = 0; mi < 4; ++mi)
#pragma unroll
        for (int jj = 0; jj < 4; ++jj) tm = fmaxf(tm, acc[mi][ni][jj]);
      tm *= SCALE;  // scale>0: max commutes with scaling
      const float mn = fmaxf(m[ni], tm);
      float add = 0.0f;
#pragma unroll
      for (int mi = 0; mi < 4; ++mi)
#pragma unroll
        for (int jj = 0; jj < 4; ++jj) add += __expf(acc[mi][ni][jj] * SCALE - mn);
      l[ni] = l[ni] * __expf(m[ni] - mn) + add;
      m[ni] = mn;
    }
  }
  // Cross-lane reduce: 8 partials per column (wr x kq), via LDS.
  __syncthreads();
  const int p = wr * 4 + kq;
#pragma unroll
  for (int ni = 0; ni < 4; ++ni) {
    const int col = wc * 64 + ni * 16 + lr;
    redM[p][col] = m[ni];
    redL[p][col] = l[ni];
  }
  __syncthreads();
  if (tid < 128) {
    float M = -3.0e38f;
#pragma unroll
    for (int q = 0; q < 8; ++q) M = fmaxf(M, redM[q][tid]);
    float L = 0.0f;
#pragma unroll
    for (int q = 0; q < 8; ++q) L += redL[q][tid] * __expf(redM[q][tid] - M);
    const size_t idx = ((size_t)ic * gridDim.z + b) * S + j0 + tid;
    mpart[idx] = M;
    lpart[idx] = L;
  }
}

extern "C" void kernel_launch(void* const* d_in, const int* in_sizes, int n_in,
                              void* d_out, int out_size, void* d_ws, size_t ws_size,
                              hipStream_t stream) {
  const float* query = (const float*)d_in[0];
  const float* key   = (const float*)d_in[1];
  const float* value = (const float*)d_in[2];
  const float* Wq    = (const float*)d_in[3];
  const float* Wk    = (const float*)d_in[4];
  const float* Wv    = (const float*)d_in[5];

  const int F = 1024;
  const int BS = in_sizes[0] / F;   // 16384
  const int B = 8;
  const int S = BS / B;             // 2048

  // ws: wq16,wk16,wv16 [F*F] + mpart,lpart [COLIC*BS] + sdiag [BS]  (~7 MB)
  _Float16* wq16 = (_Float16*)d_ws;
  _Float16* wk16 = wq16 + (size_t)F * F;
  _Float16* wv16 = wk16 + (size_t)F * F;
  float* mpart = (float*)(wv16 + (size_t)F * F);
  float* lpart = mpart + (size_t)COLIC * BS;
  float* sdiag = lpart + (size_t)COLIC * BS;

  // qt16/kt16 parked in d_out (exactly BS*F*4 bytes); dead before final GEMM writes it.
  _Float16* qt16 = (_Float16*)d_out;
  _Float16* kt16 = qt16 + (size_t)BS * F;

  const dim3 blk(256);
  const int n8w = F * F / 8;

  Conv3Args aw; aw.src[0] = Wq; aw.src[1] = Wk; aw.src[2] = Wv;
  aw.dst[0] = wq16; aw.dst[1] = wk16; aw.dst[2] = wv16;
  conv3_f32_f16<<<dim3(512, 3), blk, 0, stream>>>(aw, n8w);

  const dim3 ggrid(BS / 128, F / 128);  // 128 x 8 = 1024 blocks
  gemm_mfma<1><<<ggrid, blk, 0, stream>>>(query, wq16, qt16, (float*)nullptr,
                                          (const float*)nullptr, (const float*)nullptr,
                                          (const float*)nullptr, BS, BS, F, F);
  gemm_mfma<1><<<ggrid, blk, 0, stream>>>(key, wk16, kt16, (float*)nullptr,
                                          (const float*)nullptr, (const float*)nullptr,
                                          (const float*)nullptr, BS, BS, F, F);

  const dim3 sgrid(S / 128, COLIC, B);  // 16 x 8 x 8 = 1024 blocks
  col_stats_mfma<<<sgrid, blk, 0, stream>>>(qt16, kt16, mpart, lpart, sdiag,
                                            S, F, S / COLIC);

  gemm_mfma<0><<<ggrid, blk, 0, stream>>>(value, wv16, (_Float16*)nullptr, (float*)d_out,
                                          mpart, lpart, sdiag, BS, BS, F, F);
}

// Round 10
// 281.750 us; speedup vs baseline: 2.0173x; 1.0930x over previous
//
#include <hip/hip_runtime.h>

// B=8, S=2048, F=1024 fp32 in/out.
// out[b,s,:] = diag[b,s] * (value[b,s,:] @ Wv^T)
// diag[b,j] = exp(s_jj - M_j) / sum_i exp(s_ij - M_j),  s_ij = scale * <q_t_i, k_t_j>
// fp16 MFMA 16x16x32, 128x128 tiles, BK=64, both-sides XOR-swizzled LDS
// (R9-verified pattern), global_load_lds staging, pre-converted fp16 inputs.

typedef _Float16 f16x8 __attribute__((ext_vector_type(8)));
typedef float    f32x4 __attribute__((ext_vector_type(4)));

#define COLIC 8          // i-chunks for col_stats grid (16 x 8 x 8 = 1024 blocks)
#define SCALE 0.03125f   // 1/sqrt(1024), exact power of two

typedef __attribute__((address_space(1))) const unsigned int g_u32_t;
typedef __attribute__((address_space(3))) unsigned int l_u32_t;

__device__ __forceinline__ void gload16(const _Float16* g, _Float16* l) {
  // async global->LDS, 16 B per lane; LDS dest = wave-uniform base + lane*16
  __builtin_amdgcn_global_load_lds((g_u32_t*)g, (l_u32_t*)l, 16, 0, 0);
}

// Stage a 128x64 fp16 tile into LDS [128][64] with pre-swizzled SOURCE:
// LDS linear byte o holds logical col (o&127) ^ ((row&7)<<4)  (involution).
// Paired with read-side XOR ((lr&7)<<4); rows == lr (mod 8) at every read.
__device__ __forceinline__ void stage_tile64(const _Float16* gbase, int ldk,
                                             _Float16* lds, int w, int lane) {
#pragma unroll
  for (int c = 0; c < 4; ++c) {
    const int blk = c * 4 + w;                  // 0..15, wave-uniform
    const int o = (blk << 10) + (lane << 4);    // linear byte offset 0..16383
    const int row = o >> 7;                     // 0..127 (row = 128 B)
    const int colb = (o & 127) ^ ((row & 7) << 4);
    gload16(gbase + (size_t)row * ldk + (colb >> 1), lds + (blk << 9));
  }
}

// Batched fp32 -> fp16 conversion: grid.y selects (src,dst) pair.
struct Conv3Args {
  const float* src[3];
  _Float16* dst[3];
};
__global__ __launch_bounds__(256)
void conv3_f32_f16(Conv3Args a, int n8) {
  const float* __restrict__ src = a.src[blockIdx.y];
  _Float16* __restrict__ dst = a.dst[blockIdx.y];
  for (int i = blockIdx.x * 256 + threadIdx.x; i < n8; i += gridDim.x * 256) {
    const float4 x = ((const float4*)src)[2 * i];
    const float4 y = ((const float4*)src)[2 * i + 1];
    f16x8 o;
    o[0] = (_Float16)x.x; o[1] = (_Float16)x.y;
    o[2] = (_Float16)x.z; o[3] = (_Float16)x.w;
    o[4] = (_Float16)y.x; o[5] = (_Float16)y.y;
    o[6] = (_Float16)y.z; o[7] = (_Float16)y.w;
    ((f16x8*)dst)[i] = o;
  }
}

// C[m][n] = sum_k A[m][k] * B[n][k];  A: MxK, B: NxK, both fp16 row-major.
// F16OUT=1: write fp16 C16.  F16OUT=0: fp32 C32 scaled by fused-combine diag[m].
// BK=64, both operands via swizzled global_load_lds; 2 barriers per 64-K.
template <int F16OUT>
__global__ __launch_bounds__(256)
void gemm_mfma(const _Float16* __restrict__ A, const _Float16* __restrict__ B,
               _Float16* __restrict__ C16, float* __restrict__ C32,
               const float* __restrict__ mpart, const float* __restrict__ lpart,
               const float* __restrict__ sdiag, int BSz,
               int M, int N, int Kd) {
  __shared__ __align__(16) _Float16 As[128 * 64];   // 16 KB each
  __shared__ __align__(16) _Float16 Bs[128 * 64];
  __shared__ float diagS[128];
  const int tid = threadIdx.x;
  const int w = tid >> 6, lane = tid & 63;
  const int wr = w >> 1, wc = w & 1;          // 2x2 waves over 128x128
  const int lr = lane & 15, kq = lane >> 4;
  const int swz = (lr & 7) << 4;              // read-side XOR
  const int bm = blockIdx.x * 128, bn = blockIdx.y * 128;

  if (!F16OUT && tid < 128) {
    const int row = bm + tid;
    float Mx = -3.0e38f;
#pragma unroll
    for (int c = 0; c < COLIC; ++c) Mx = fmaxf(Mx, mpart[(size_t)c * BSz + row]);
    float L = 0.0f;
#pragma unroll
    for (int c = 0; c < COLIC; ++c)
      L += lpart[(size_t)c * BSz + row] * __expf(mpart[(size_t)c * BSz + row] - Mx);
    diagS[tid] = __expf(sdiag[row] - Mx) / L;
  }

  f32x4 acc[4][4] = {};
  for (int k0 = 0; k0 < Kd; k0 += 64) {
    stage_tile64(A + (size_t)bm * Kd + k0, Kd, As, w, lane);
    stage_tile64(B + (size_t)bn * Kd + k0, Kd, Bs, w, lane);
    __syncthreads();
    f16x8 af[4][2], bf[4][2];
#pragma unroll
    for (int mi = 0; mi < 4; ++mi) {
      const int ro = (wr * 64 + mi * 16 + lr) << 7;   // row byte base
      af[mi][0] = *(const f16x8*)&As[(ro + ((kq * 16) ^ swz)) >> 1];
      af[mi][1] = *(const f16x8*)&As[(ro + ((64 + kq * 16) ^ swz)) >> 1];
    }
#pragma unroll
    for (int ni = 0; ni < 4; ++ni) {
      const int ro = (wc * 64 + ni * 16 + lr) << 7;
      bf[ni][0] = *(const f16x8*)&Bs[(ro + ((kq * 16) ^ swz)) >> 1];
      bf[ni][1] = *(const f16x8*)&Bs[(ro + ((64 + kq * 16) ^ swz)) >> 1];
    }
#pragma unroll
    for (int ks = 0; ks < 2; ++ks)
#pragma unroll
      for (int mi = 0; mi < 4; ++mi)
#pragma unroll
        for (int ni = 0; ni < 4; ++ni)
          acc[mi][ni] = __builtin_amdgcn_mfma_f32_16x16x32_f16(af[mi][ks], bf[ni][ks], acc[mi][ni], 0, 0, 0);
    __syncthreads();   // also keeps diagS visible for epilogue
  }
  // C/D layout: col = lane&15, row = (lane>>4)*4 + reg  [m89-verified]
#pragma unroll
  for (int mi = 0; mi < 4; ++mi) {
#pragma unroll
    for (int j = 0; j < 4; ++j) {
      const int rloc = wr * 64 + mi * 16 + kq * 4 + j;
      const int row = bm + rloc;
      float s = 1.0f;
      if (!F16OUT) s = diagS[rloc];
#pragma unroll
      for (int ni = 0; ni < 4; ++ni) {
        const int col = bn + wc * 64 + ni * 16 + lr;
        if (F16OUT) C16[(size_t)row * N + col] = (_Float16)acc[mi][ni][j];
        else        C32[(size_t)row * N + col] = acc[mi][ni][j] * s;
      }
    }
  }
}

// Per (b, j-tile 128, i-chunk): S-tile = Qt * Kt^T via MFMA (never materialized),
// online per-column (max, sumexp) over i, diag capture. BK=64, single-buffered,
// XOR-swizzled LDS. (R9-identical: 110 µs, 65K bank conflicts.)
__global__ __launch_bounds__(256)
void col_stats_mfma(const _Float16* __restrict__ qt, const _Float16* __restrict__ kt,
                    float* __restrict__ mpart, float* __restrict__ lpart,
                    float* __restrict__ sdiag, int S, int Fd, int chunk) {
  __shared__ __align__(16) _Float16 Qs[128 * 64];
  __shared__ __align__(16) _Float16 Ks[128 * 64];
  __shared__ float redM[8][128];
  __shared__ float redL[8][128];
  const int b = blockIdx.z, jb = blockIdx.x, ic = blockIdx.y;
  const int j0 = jb * 128;
  const _Float16* Q = qt + (size_t)b * S * Fd;
  const _Float16* K = kt + (size_t)b * S * Fd;
  const int tid = threadIdx.x;
  const int w = tid >> 6, lane = tid & 63;
  const int wr = w >> 1, wc = w & 1;
  const int lr = lane & 15, kq = lane >> 4;
  const int swz = (lr & 7) << 4;

  float m[4], l[4];
#pragma unroll
  for (int ni = 0; ni < 4; ++ni) { m[ni] = -3.0e38f; l[ni] = 0.0f; }

  for (int it = 0; it < chunk >> 7; ++it) {
    const int i0 = ic * chunk + (it << 7);
    f32x4 acc[4][4] = {};
    for (int k0 = 0; k0 < Fd; k0 += 64) {
      stage_tile64(Q + (size_t)i0 * Fd + k0, Fd, Qs, w, lane);
      stage_tile64(K + (size_t)j0 * Fd + k0, Fd, Ks, w, lane);
      __syncthreads();
      f16x8 af[4][2], bf[4][2];
#pragma unroll
      for (int mi = 0; mi < 4; ++mi) {
        const int ro = (wr * 64 + mi * 16 + lr) << 7;
        af[mi][0] = *(const f16x8*)&Qs[(ro + ((kq * 16) ^ swz)) >> 1];
        af[mi][1] = *(const f16x8*)&Qs[(ro + ((64 + kq * 16) ^ swz)) >> 1];
      }
#pragma unroll
      for (int ni = 0; ni < 4; ++ni) {
        const int ro = (wc * 64 + ni * 16 + lr) << 7;
        bf[ni][0] = *(const f16x8*)&Ks[(ro + ((kq * 16) ^ swz)) >> 1];
        bf[ni][1] = *(const f16x8*)&Ks[(ro + ((64 + kq * 16) ^ swz)) >> 1];
      }
#pragma unroll
      for (int ks = 0; ks < 2; ++ks)
#pragma unroll
        for (int mi = 0; mi < 4; ++mi)
#pragma unroll
          for (int ni = 0; ni < 4; ++ni)
            acc[mi][ni] = __builtin_amdgcn_mfma_f32_16x16x32_f16(af[mi][ks], bf[ni][ks], acc[mi][ni], 0, 0, 0);
      __syncthreads();
    }
    // Diagonal capture (i-tile == j-tile, diagonal micro-fragments).
    if (i0 == j0 && wr == wc && (lr >> 2) == kq) {
      const int j = lr & 3;
#pragma unroll
      for (int jj = 0; jj < 4; ++jj)
        sdiag[(size_t)b * S + j0 + wc * 64 + jj * 16 + lr] = acc[jj][jj][j] * SCALE;
    }
    // Online (m,l) update: per lane, 4 columns (ni), 16 i-values each.
#pragma unroll
    for (int ni = 0; ni < 4; ++ni) {
      float tm = -3.0e38f;
#pragma unroll
      for (int mi = 0; mi < 4; ++mi)
#pragma unroll
        for (int jj = 0; jj < 4; ++jj) tm = fmaxf(tm, acc[mi][ni][jj]);
      tm *= SCALE;  // scale>0: max commutes with scaling
      const float mn = fmaxf(m[ni], tm);
      float add = 0.0f;
#pragma unroll
      for (int mi = 0; mi < 4; ++mi)
#pragma unroll
        for (int jj = 0; jj < 4; ++jj) add += __expf(acc[mi][ni][jj] * SCALE - mn);
      l[ni] = l[ni] * __expf(m[ni] - mn) + add;
      m[ni] = mn;
    }
  }
  // Cross-lane reduce: 8 partials per column (wr x kq), via LDS.
  __syncthreads();
  const int p = wr * 4 + kq;
#pragma unroll
  for (int ni = 0; ni < 4; ++ni) {
    const int col = wc * 64 + ni * 16 + lr;
    redM[p][col] = m[ni];
    redL[p][col] = l[ni];
  }
  __syncthreads();
  if (tid < 128) {
    float M = -3.0e38f;
#pragma unroll
    for (int q = 0; q < 8; ++q) M = fmaxf(M, redM[q][tid]);
    float L = 0.0f;
#pragma unroll
    for (int q = 0; q < 8; ++q) L += redL[q][tid] * __expf(redM[q][tid] - M);
    const size_t idx = ((size_t)ic * gridDim.z + b) * S + j0 + tid;
    mpart[idx] = M;
    lpart[idx] = L;
  }
}

extern "C" void kernel_launch(void* const* d_in, const int* in_sizes, int n_in,
                              void* d_out, int out_size, void* d_ws, size_t ws_size,
                              hipStream_t stream) {
  const float* query = (const float*)d_in[0];
  const float* key   = (const float*)d_in[1];
  const float* value = (const float*)d_in[2];
  const float* Wq    = (const float*)d_in[3];
  const float* Wk    = (const float*)d_in[4];
  const float* Wv    = (const float*)d_in[5];

  const int F = 1024;
  const int BS = in_sizes[0] / F;   // 16384
  const int B = 8;
  const int S = BS / B;             // 2048

  // ws: q16,k16,v16 [BS*F] wq16,wk16,wv16 [F*F] mpart,lpart [COLIC*BS] sdiag [BS]
  _Float16* q16  = (_Float16*)d_ws;
  _Float16* k16  = q16 + (size_t)BS * F;
  _Float16* v16  = k16 + (size_t)BS * F;
  _Float16* wq16 = v16 + (size_t)BS * F;
  _Float16* wk16 = wq16 + (size_t)F * F;
  _Float16* wv16 = wk16 + (size_t)F * F;
  float* mpart = (float*)(wv16 + (size_t)F * F);
  float* lpart = mpart + (size_t)COLIC * BS;
  float* sdiag = lpart + (size_t)COLIC * BS;

  // qt16/kt16 parked in d_out (exactly BS*F*4 bytes); dead before final GEMM writes it.
  _Float16* qt16 = (_Float16*)d_out;
  _Float16* kt16 = qt16 + (size_t)BS * F;

  const dim3 blk(256);
  const int n8x = BS * F / 8, n8w = F * F / 8;

  Conv3Args ax; ax.src[0] = query; ax.src[1] = key; ax.src[2] = value;
  ax.dst[0] = q16; ax.dst[1] = k16; ax.dst[2] = v16;
  conv3_f32_f16<<<dim3(2048, 3), blk, 0, stream>>>(ax, n8x);

  Conv3Args aw; aw.src[0] = Wq; aw.src[1] = Wk; aw.src[2] = Wv;
  aw.dst[0] = wq16; aw.dst[1] = wk16; aw.dst[2] = wv16;
  conv3_f32_f16<<<dim3(512, 3), blk, 0, stream>>>(aw, n8w);

  const dim3 ggrid(BS / 128, F / 128);  // 128 x 8 = 1024 blocks
  gemm_mfma<1><<<ggrid, blk, 0, stream>>>(q16, wq16, qt16, (float*)nullptr,
                                          (const float*)nullptr, (const float*)nullptr,
                                          (const float*)nullptr, BS, BS, F, F);
  gemm_mfma<1><<<ggrid, blk, 0, stream>>>(k16, wk16, kt16, (float*)nullptr,
                                          (const float*)nullptr, (const float*)nullptr,
                                          (const float*)nullptr, BS, BS, F, F);

  const dim3 sgrid(S / 128, COLIC, B);  // 16 x 8 x 8 = 1024 blocks
  col_stats_mfma<<<sgrid, blk, 0, stream>>>(qt16, kt16, mpart, lpart, sdiag,
                                            S, F, S / COLIC);

  gemm_mfma<0><<<ggrid, blk, 0, stream>>>(v16, wv16, (_Float16*)nullptr, (float*)d_out,
                                          mpart, lpart, sdiag, BS, BS, F, F);
}

// Round 11
// 270.823 us; speedup vs baseline: 2.0987x; 1.0403x over previous
//
#include <hip/hip_runtime.h>

// B=8, S=2048, F=1024 fp32 in/out.
// out[b,s,:] = diag[b,s] * (value[b,s,:] @ Wv^T)
// diag[b,j] = exp(s_jj - M_j) / sum_i exp(s_ij - M_j)
// Factorized scores: s_ij = <q16_i, kt2_j>, kt2 = k16 @ W2^T(row-form), W2 = Wq^T Wk.
// This removes the q-projection GEMM entirely (associativity).
// fp16 MFMA 16x16x32, 128x128 tiles, BK=64, both-sides XOR-swizzled LDS,
// global_load_lds staging. col_stats gets an XCD-aware block remap (L2 locality).

typedef _Float16 f16x8 __attribute__((ext_vector_type(8)));
typedef float    f32x4 __attribute__((ext_vector_type(4)));

#define COLIC 8          // i-chunks for col_stats grid (16 x 8 x 8 = 1024 blocks)
#define SCALE 0.03125f   // 1/sqrt(1024), exact power of two

typedef __attribute__((address_space(1))) const unsigned int g_u32_t;
typedef __attribute__((address_space(3))) unsigned int l_u32_t;

__device__ __forceinline__ void gload16(const _Float16* g, _Float16* l) {
  // async global->LDS, 16 B per lane; LDS dest = wave-uniform base + lane*16
  __builtin_amdgcn_global_load_lds((g_u32_t*)g, (l_u32_t*)l, 16, 0, 0);
}

// Stage a 128x64 fp16 tile into LDS [128][64] with pre-swizzled SOURCE:
// LDS linear byte o holds logical col (o&127) ^ ((row&7)<<4)  (involution).
// Paired with read-side XOR ((lr&7)<<4); rows == lr (mod 8) at every read.
__device__ __forceinline__ void stage_tile64(const _Float16* gbase, int ldk,
                                             _Float16* lds, int w, int lane) {
#pragma unroll
  for (int c = 0; c < 4; ++c) {
    const int blk = c * 4 + w;                  // 0..15, wave-uniform
    const int o = (blk << 10) + (lane << 4);    // linear byte offset 0..16383
    const int row = o >> 7;                     // 0..127 (row = 128 B)
    const int colb = (o & 127) ^ ((row & 7) << 4);
    gload16(gbase + (size_t)row * ldk + (colb >> 1), lds + (blk << 9));
  }
}

// Batched fp32 -> fp16 conversion: grid.y selects (src,dst) pair.
struct Conv3Args {
  const float* src[3];
  _Float16* dst[3];
};
__global__ __launch_bounds__(256)
void conv3_f32_f16(Conv3Args a, int n8) {
  const float* __restrict__ src = a.src[blockIdx.y];
  _Float16* __restrict__ dst = a.dst[blockIdx.y];
  for (int i = blockIdx.x * 256 + threadIdx.x; i < n8; i += gridDim.x * 256) {
    const float4 x = ((const float4*)src)[2 * i];
    const float4 y = ((const float4*)src)[2 * i + 1];
    f16x8 o;
    o[0] = (_Float16)x.x; o[1] = (_Float16)x.y;
    o[2] = (_Float16)x.z; o[3] = (_Float16)x.w;
    o[4] = (_Float16)y.x; o[5] = (_Float16)y.y;
    o[6] = (_Float16)y.z; o[7] = (_Float16)y.w;
    ((f16x8*)dst)[i] = o;
  }
}

// Transposing fp32 -> fp16 conversion for 1024x1024 weights: dst[f][g] = src[g][f].
struct Conv2Args {
  const float* src[2];
  _Float16* dst[2];
};
__global__ __launch_bounds__(256)
void convT_f32_f16(Conv2Args a) {
  __shared__ float Ts[64][65];
  const float* __restrict__ src = a.src[blockIdx.z];
  _Float16* __restrict__ dst = a.dst[blockIdx.z];
  const int g0 = blockIdx.x * 64, f0 = blockIdx.y * 64;
  const int tid = threadIdx.x;
  {
    const int r = tid >> 4;          // 0..15
    const int c4 = (tid & 15) << 2;  // 0..60
#pragma unroll
    for (int p = 0; p < 4; ++p) {
      const int row = p * 16 + r;
      const float4 v = *(const float4*)&src[(size_t)(g0 + row) * 1024 + f0 + c4];
      Ts[row][c4 + 0] = v.x; Ts[row][c4 + 1] = v.y;
      Ts[row][c4 + 2] = v.z; Ts[row][c4 + 3] = v.w;
    }
  }
  __syncthreads();
  {
    const int f = tid >> 3;          // 0..31
    const int gs = (tid & 7) << 3;   // 0..56
#pragma unroll
    for (int p = 0; p < 2; ++p) {
      const int fr = p * 32 + f;
      f16x8 v;
#pragma unroll
      for (int j = 0; j < 8; ++j) v[j] = (_Float16)Ts[gs + j][fr];
      *(f16x8*)&dst[(size_t)(f0 + fr) * 1024 + g0 + gs] = v;
    }
  }
}

// C[m][n] = sum_k A[m][k] * B[n][k];  A: MxK, B: NxK, both fp16 row-major.
// F16OUT=1: write fp16 C16.  F16OUT=0: fp32 C32 scaled by fused-combine diag[m].
// BK=64, both operands via swizzled global_load_lds; 2 barriers per 64-K. (R10)
template <int F16OUT>
__global__ __launch_bounds__(256)
void gemm_mfma(const _Float16* __restrict__ A, const _Float16* __restrict__ B,
               _Float16* __restrict__ C16, float* __restrict__ C32,
               const float* __restrict__ mpart, const float* __restrict__ lpart,
               const float* __restrict__ sdiag, int BSz,
               int M, int N, int Kd) {
  __shared__ __align__(16) _Float16 As[128 * 64];   // 16 KB each
  __shared__ __align__(16) _Float16 Bs[128 * 64];
  __shared__ float diagS[128];
  const int tid = threadIdx.x;
  const int w = tid >> 6, lane = tid & 63;
  const int wr = w >> 1, wc = w & 1;          // 2x2 waves over 128x128
  const int lr = lane & 15, kq = lane >> 4;
  const int swz = (lr & 7) << 4;              // read-side XOR
  const int bm = blockIdx.x * 128, bn = blockIdx.y * 128;

  if (!F16OUT && tid < 128) {
    const int row = bm + tid;
    float Mx = -3.0e38f;
#pragma unroll
    for (int c = 0; c < COLIC; ++c) Mx = fmaxf(Mx, mpart[(size_t)c * BSz + row]);
    float L = 0.0f;
#pragma unroll
    for (int c = 0; c < COLIC; ++c)
      L += lpart[(size_t)c * BSz + row] * __expf(mpart[(size_t)c * BSz + row] - Mx);
    diagS[tid] = __expf(sdiag[row] - Mx) / L;
  }

  f32x4 acc[4][4] = {};
  for (int k0 = 0; k0 < Kd; k0 += 64) {
    stage_tile64(A + (size_t)bm * Kd + k0, Kd, As, w, lane);
    stage_tile64(B + (size_t)bn * Kd + k0, Kd, Bs, w, lane);
    __syncthreads();
    f16x8 af[4][2], bf[4][2];
#pragma unroll
    for (int mi = 0; mi < 4; ++mi) {
      const int ro = (wr * 64 + mi * 16 + lr) << 7;   // row byte base
      af[mi][0] = *(const f16x8*)&As[(ro + ((kq * 16) ^ swz)) >> 1];
      af[mi][1] = *(const f16x8*)&As[(ro + ((64 + kq * 16) ^ swz)) >> 1];
    }
#pragma unroll
    for (int ni = 0; ni < 4; ++ni) {
      const int ro = (wc * 64 + ni * 16 + lr) << 7;
      bf[ni][0] = *(const f16x8*)&Bs[(ro + ((kq * 16) ^ swz)) >> 1];
      bf[ni][1] = *(const f16x8*)&Bs[(ro + ((64 + kq * 16) ^ swz)) >> 1];
    }
#pragma unroll
    for (int ks = 0; ks < 2; ++ks)
#pragma unroll
      for (int mi = 0; mi < 4; ++mi)
#pragma unroll
        for (int ni = 0; ni < 4; ++ni)
          acc[mi][ni] = __builtin_amdgcn_mfma_f32_16x16x32_f16(af[mi][ks], bf[ni][ks], acc[mi][ni], 0, 0, 0);
    __syncthreads();   // also keeps diagS visible for epilogue
  }
  // C/D layout: col = lane&15, row = (lane>>4)*4 + reg  [m89-verified]
#pragma unroll
  for (int mi = 0; mi < 4; ++mi) {
#pragma unroll
    for (int j = 0; j < 4; ++j) {
      const int rloc = wr * 64 + mi * 16 + kq * 4 + j;
      const int row = bm + rloc;
      float s = 1.0f;
      if (!F16OUT) s = diagS[rloc];
#pragma unroll
      for (int ni = 0; ni < 4; ++ni) {
        const int col = bn + wc * 64 + ni * 16 + lr;
        if (F16OUT) C16[(size_t)row * N + col] = (_Float16)acc[mi][ni][j];
        else        C32[(size_t)row * N + col] = acc[mi][ni][j] * s;
      }
    }
  }
}

// Per (b, j-tile 128, i-chunk): S-tile = q16 * kt2^T via MFMA (never materialized),
// online per-column (max, sumexp) over i, diag capture. BK=64, single-buffered,
// XOR-swizzled LDS. XCD-aware remap: id%8 == jb>>1 -> each XCD owns 2 j-tiles
// (kt2 slice 4MB = its L2) and co-locates both readers of each q-chunk.
__global__ __launch_bounds__(256)
void col_stats_mfma(const _Float16* __restrict__ qt, const _Float16* __restrict__ kt,
                    float* __restrict__ mpart, float* __restrict__ lpart,
                    float* __restrict__ sdiag, int S, int Fd, int chunk) {
  __shared__ __align__(16) _Float16 Qs[128 * 64];
  __shared__ __align__(16) _Float16 Ks[128 * 64];
  __shared__ float redM[8][128];
  __shared__ float redL[8][128];
  // bijective remap of the 1024-block grid (16 x 8 x 8)
  const int t = blockIdx.x + 16 * (blockIdx.y + 8 * blockIdx.z);  // linear id
  const int jb = ((t & 7) << 1) | ((t >> 3) & 1);
  const int rr = t >> 4;
  const int ic = rr & 7;
  const int b  = rr >> 3;
  const int j0 = jb * 128;
  const _Float16* Q = qt + (size_t)b * S * Fd;
  const _Float16* K = kt + (size_t)b * S * Fd;
  const int tid = threadIdx.x;
  const int w = tid >> 6, lane = tid & 63;
  const int wr = w >> 1, wc = w & 1;
  const int lr = lane & 15, kq = lane >> 4;
  const int swz = (lr & 7) << 4;

  float m[4], l[4];
#pragma unroll
  for (int ni = 0; ni < 4; ++ni) { m[ni] = -3.0e38f; l[ni] = 0.0f; }

  for (int it = 0; it < chunk >> 7; ++it) {
    const int i0 = ic * chunk + (it << 7);
    f32x4 acc[4][4] = {};
    for (int k0 = 0; k0 < Fd; k0 += 64) {
      stage_tile64(Q + (size_t)i0 * Fd + k0, Fd, Qs, w, lane);
      stage_tile64(K + (size_t)j0 * Fd + k0, Fd, Ks, w, lane);
      __syncthreads();
      f16x8 af[4][2], bf[4][2];
#pragma unroll
      for (int mi = 0; mi < 4; ++mi) {
        const int ro = (wr * 64 + mi * 16 + lr) << 7;
        af[mi][0] = *(const f16x8*)&Qs[(ro + ((kq * 16) ^ swz)) >> 1];
        af[mi][1] = *(const f16x8*)&Qs[(ro + ((64 + kq * 16) ^ swz)) >> 1];
      }
#pragma unroll
      for (int ni = 0; ni < 4; ++ni) {
        const int ro = (wc * 64 + ni * 16 + lr) << 7;
        bf[ni][0] = *(const f16x8*)&Ks[(ro + ((kq * 16) ^ swz)) >> 1];
        bf[ni][1] = *(const f16x8*)&Ks[(ro + ((64 + kq * 16) ^ swz)) >> 1];
      }
#pragma unroll
      for (int ks = 0; ks < 2; ++ks)
#pragma unroll
        for (int mi = 0; mi < 4; ++mi)
#pragma unroll
          for (int ni = 0; ni < 4; ++ni)
            acc[mi][ni] = __builtin_amdgcn_mfma_f32_16x16x32_f16(af[mi][ks], bf[ni][ks], acc[mi][ni], 0, 0, 0);
      __syncthreads();
    }
    // Diagonal capture (i-tile == j-tile, diagonal micro-fragments).
    if (i0 == j0 && wr == wc && (lr >> 2) == kq) {
      const int j = lr & 3;
#pragma unroll
      for (int jj = 0; jj < 4; ++jj)
        sdiag[(size_t)b * S + j0 + wc * 64 + jj * 16 + lr] = acc[jj][jj][j] * SCALE;
    }
    // Online (m,l) update: per lane, 4 columns (ni), 16 i-values each.
#pragma unroll
    for (int ni = 0; ni < 4; ++ni) {
      float tm = -3.0e38f;
#pragma unroll
      for (int mi = 0; mi < 4; ++mi)
#pragma unroll
        for (int jj = 0; jj < 4; ++jj) tm = fmaxf(tm, acc[mi][ni][jj]);
      tm *= SCALE;  // scale>0: max commutes with scaling
      const float mn = fmaxf(m[ni], tm);
      float add = 0.0f;
#pragma unroll
      for (int mi = 0; mi < 4; ++mi)
#pragma unroll
        for (int jj = 0; jj < 4; ++jj) add += __expf(acc[mi][ni][jj] * SCALE - mn);
      l[ni] = l[ni] * __expf(m[ni] - mn) + add;
      m[ni] = mn;
    }
  }
  // Cross-lane reduce: 8 partials per column (wr x kq), via LDS.
  __syncthreads();
  const int p = wr * 4 + kq;
#pragma unroll
  for (int ni = 0; ni < 4; ++ni) {
    const int col = wc * 64 + ni * 16 + lr;
    redM[p][col] = m[ni];
    redL[p][col] = l[ni];
  }
  __syncthreads();
  if (tid < 128) {
    float M = -3.0e38f;
#pragma unroll
    for (int q = 0; q < 8; ++q) M = fmaxf(M, redM[q][tid]);
    float L = 0.0f;
#pragma unroll
    for (int q = 0; q < 8; ++q) L += redL[q][tid] * __expf(redM[q][tid] - M);
    const size_t idx = ((size_t)ic * 8 + b) * S + j0 + tid;
    mpart[idx] = M;
    lpart[idx] = L;
  }
}

extern "C" void kernel_launch(void* const* d_in, const int* in_sizes, int n_in,
                              void* d_out, int out_size, void* d_ws, size_t ws_size,
                              hipStream_t stream) {
  const float* query = (const float*)d_in[0];
  const float* key   = (const float*)d_in[1];
  const float* value = (const float*)d_in[2];
  const float* Wq    = (const float*)d_in[3];
  const float* Wk    = (const float*)d_in[4];
  const float* Wv    = (const float*)d_in[5];

  const int F = 1024;
  const int BS = in_sizes[0] / F;   // 16384
  const int B = 8;
  const int S = BS / B;             // 2048

  // ws: q16,k16,v16 [BS*F] wqT16,wkT16,wv16,W2 [F*F] mpart,lpart [COLIC*BS] sdiag [BS]
  _Float16* q16   = (_Float16*)d_ws;
  _Float16* k16   = q16 + (size_t)BS * F;
  _Float16* v16   = k16 + (size_t)BS * F;
  _Float16* wqT16 = v16 + (size_t)BS * F;
  _Float16* wkT16 = wqT16 + (size_t)F * F;
  _Float16* wv16  = wkT16 + (size_t)F * F;
  _Float16* W2h   = wv16 + (size_t)F * F;
  float* mpart = (float*)(W2h + (size_t)F * F);
  float* lpart = mpart + (size_t)COLIC * BS;
  float* sdiag = lpart + (size_t)COLIC * BS;

  // kt2 parked in d_out's first half (BS*F fp16 = 32MB of 64MB); dead before
  // the final V-GEMM overwrites d_out.
  _Float16* kt2 = (_Float16*)d_out;

  const dim3 blk(256);
  const int n8x = BS * F / 8, n8w = F * F / 8;

  // input conversions
  Conv3Args ax; ax.src[0] = query; ax.src[1] = key; ax.src[2] = value;
  ax.dst[0] = q16; ax.dst[1] = k16; ax.dst[2] = v16;
  conv3_f32_f16<<<dim3(2048, 3), blk, 0, stream>>>(ax, n8x);

  Conv3Args av; av.src[0] = Wv; av.dst[0] = wv16;
  conv3_f32_f16<<<dim3(512, 1), blk, 0, stream>>>(av, n8w);

  Conv2Args at; at.src[0] = Wq; at.src[1] = Wk;
  at.dst[0] = wqT16; at.dst[1] = wkT16;
  convT_f32_f16<<<dim3(16, 16, 2), blk, 0, stream>>>(at);

  // W2 = Wq^T Wk  (1024x1024)
  gemm_mfma<1><<<dim3(8, 8), blk, 0, stream>>>(wqT16, wkT16, W2h, (float*)nullptr,
                                               (const float*)nullptr, (const float*)nullptr,
                                               (const float*)nullptr, 0, F, F, F);

  // kt2[j,f] = sum_f' k16[j,f'] W2[f,f']
  gemm_mfma<1><<<dim3(BS / 128, F / 128), blk, 0, stream>>>(k16, W2h, kt2, (float*)nullptr,
                                               (const float*)nullptr, (const float*)nullptr,
                                               (const float*)nullptr, 0, BS, F, F);

  // column stats of s = scale * q16 @ kt2^T
  const dim3 sgrid(S / 128, COLIC, B);  // 16 x 8 x 8 = 1024 blocks (remapped inside)
  col_stats_mfma<<<sgrid, blk, 0, stream>>>(q16, kt2, mpart, lpart, sdiag,
                                            S, F, S / COLIC);

  // out = diag * (v16 @ Wv^T), diag combined in-prologue
  gemm_mfma<0><<<dim3(BS / 128, F / 128), blk, 0, stream>>>(v16, wv16, (_Float16*)nullptr,
                                               (float*)d_out, mpart, lpart, sdiag,
                                               BS, BS, F, F);
}